// Round 16
// baseline (122.355 us; speedup 1.0000x reference)
//
#include <hip/hip_runtime.h>
#include <hip/hip_bf16.h>

typedef __attribute__((ext_vector_type(8))) int   i32x8;   // 32 B = fp8 MFMA A/B operand (8 VGPRs)
typedef __attribute__((ext_vector_type(4))) int   i32x4;
typedef __attribute__((ext_vector_type(4))) float f32x4;   // MFMA C/D

constexpr int BB = 4096;   // batch B
constexpr int D  = 256;    // feature dim
constexpr int R2 = 8192;   // 2B rows of z
constexpr int TB = 256;    // tile edge
constexpr int NTILE = 32;  // R2 / TB
constexpr int NBLK = NTILE * (NTILE + 1) / 2;   // 528 triangular blocks
constexpr int NG = TB / 16;                     // 16 n-groups per wave
// z pre-scaled by sqrt(2*log2(e)): dot = log2(e)*sim/TEMP -> exp2(dot) = exp(sim/TEMP).
constexpr float SCALE = 1.6986436005760381f;
constexpr float E2 = 7.38905609893065f;  // exp(2) == exp(diag sim)

// Async 16B/lane global->LDS DMA. LDS dest is wave-uniform base + lane*16 (HW).
__device__ __forceinline__ void async16(const unsigned char* g, unsigned char* l) {
    __builtin_amdgcn_global_load_lds(
        (const __attribute__((address_space(1))) void*)g,
        (__attribute__((address_space(3))) void*)l,
        16, 0, 0);
}

// Unit-scale (E8M0 127 = 2^0) MX-fp8 MFMA, fmt A/B = fp8-e4m3. Verified correct R5-R15.
#define MFMA8(A, B, C) \
    __builtin_amdgcn_mfma_scale_f32_16x16x128_f8f6f4((A), (B), (C), 0, 0, 0, 127, 0, 127)

// Kernel A: L2-normalize rows, scale by sqrt(2*log2e), store fp8-e4m3 z[8192][256];
// pos[k] = 2*cos(xi_k, xj_k). Blocks 0-31 also zero S[8192]; block 0 zeros out[0].
__global__ __launch_bounds__(256) void norm_kernel(const float* __restrict__ xi,
                                                   const float* __restrict__ xj,
                                                   int* __restrict__ z8,
                                                   float* __restrict__ pos,
                                                   float* __restrict__ S,
                                                   float* __restrict__ out) {
    const int wid = threadIdx.x >> 6, lane = threadIdx.x & 63;
    const int k = blockIdx.x * 4 + wid;
    if (blockIdx.x == 0 && threadIdx.x == 0) out[0] = 0.f;
    if (blockIdx.x < 32) S[blockIdx.x * 256 + threadIdx.x] = 0.f;
    const float4* a4 = reinterpret_cast<const float4*>(xi + (size_t)k * D);
    const float4* b4 = reinterpret_cast<const float4*>(xj + (size_t)k * D);
    float4 a = a4[lane], b = b4[lane];
    float ssi = a.x*a.x + a.y*a.y + a.z*a.z + a.w*a.w;
    float ssj = b.x*b.x + b.y*b.y + b.z*b.z + b.w*b.w;
    float dot = a.x*b.x + a.y*b.y + a.z*b.z + a.w*b.w;
#pragma unroll
    for (int off = 32; off; off >>= 1) {
        ssi += __shfl_xor(ssi, off);
        ssj += __shfl_xor(ssj, off);
        dot += __shfl_xor(dot, off);
    }
    const float inv_i = 1.0f / fmaxf(sqrtf(ssi), 1e-12f);
    const float inv_j = 1.0f / fmaxf(sqrtf(ssj), 1e-12f);
    const float si = inv_i * SCALE, sj = inv_j * SCALE;
    int pi = __builtin_amdgcn_cvt_pk_fp8_f32(a.x*si, a.y*si, 0, false);
    pi     = __builtin_amdgcn_cvt_pk_fp8_f32(a.z*si, a.w*si, pi, true);
    int pj = __builtin_amdgcn_cvt_pk_fp8_f32(b.x*sj, b.y*sj, 0, false);
    pj     = __builtin_amdgcn_cvt_pk_fp8_f32(b.z*sj, b.w*sj, pj, true);
    z8[(size_t)k * 64 + lane]        = pi;
    z8[(size_t)(k + BB) * 64 + lane] = pj;
    if (lane == 0) pos[k] = dot * inv_i * inv_j * 2.0f;
}

// Kernel B (dense triangular): 528 blocks, linear t -> (bi,bj), bi<=bj. Computes
// tile exp(z_I . z_J^T) once; row-sums -> S[rows I], col-sums -> S[rows J] (symmetry).
// R15 post-mortem: occupancy 4.8% (machine ~80% empty) — suspects were 496 dead
// early-exit blocks churning 64 KB LDS slots through the CP, and a per-group serial
// chain (ds_read wait -> MFMA -> exp -> in-loop shfl w/ lgkm waits) that 2 waves/SIMD
// can't hide. Fixes: (1) no dead blocks (dense 1-D triangular grid; consecutive t
// share bj -> col-tile L2 reuse); (2) col-sum shfl deferred to epilogue — inner loop
// has NO cross-lane ops; (3) next group's ds_reads issue before current group's
// MFMAs (ILP over the ~120cyc LDS latency). Skeleton else = R14/R15: 64 KB LDS cap
// -> 2 blocks/CU -> allocator keeps honest 256-reg budget (VGPR 184 measured, 0 spills).
// fp8 layouts + unit scales + DMA/read swizzles verified R5-R15; A-frag pin (R9/R10).
__global__ __launch_bounds__(256) void sim_kernel(const unsigned char* __restrict__ z8,
                                                  float* __restrict__ S) {
    __shared__ unsigned char tb[TB * D];       // 64 KB -> LDS-capped 2 blocks/CU
    const int t = blockIdx.x;
    // t -> (bi, bj), bi <= bj: bj = row of the triangle, bi = t - bj(bj+1)/2.
    int bj = (int)((sqrtf(8.0f * (float)t + 1.0f) - 1.0f) * 0.5f);
    while ((bj + 1) * (bj + 2) / 2 <= t) ++bj;
    while (bj * (bj + 1) / 2 > t) --bj;
    const int bi = t - bj * (bj + 1) / 2;
    const int tid = threadIdx.x;
    const int wid = tid >> 6, lane = tid & 63;
    const int lrow = lane & 15, quad = lane >> 4;
    const int r0 = bi * TB + wid * 64;         // this wave's 64 rows
    const int cbase = bj * TB;                 // this block's 256 cols
    const bool offdiag = (bj != bi);

    // Staging (verified): round i stages rows i*16 + (tid>>4); physical granule
    // p = tid&15 (forced dest tb + i*4096 + tid*16) <- logical p ^ (row&15).
    {
        const int srow16 = tid >> 4;
        const int srcg   = (tid & 15) ^ srow16;
        const unsigned char* gs = z8 + (size_t)(cbase + srow16) * D + srcg * 16;
        unsigned char* ds = tb + tid * 16;
#pragma unroll
        for (int i = 0; i < 16; ++i)
            async16(gs + (size_t)i * 16 * D, ds + i * 4096);
    }

    // A fragments: 64 rows x K=256 (row = lane&15, k = quad*32 + linear; half1 +128).
    const unsigned char* abase = z8 + (size_t)(r0 + lrow) * D + quad * 32;
    i32x8 a0k0 = *reinterpret_cast<const i32x8*>(abase             );
    i32x8 a0k1 = *reinterpret_cast<const i32x8*>(abase        + 128);
    i32x8 a1k0 = *reinterpret_cast<const i32x8*>(abase + 16*D      );
    i32x8 a1k1 = *reinterpret_cast<const i32x8*>(abase + 16*D + 128);
    i32x8 a2k0 = *reinterpret_cast<const i32x8*>(abase + 32*D      );
    i32x8 a2k1 = *reinterpret_cast<const i32x8*>(abase + 32*D + 128);
    i32x8 a3k0 = *reinterpret_cast<const i32x8*>(abase + 48*D      );
    i32x8 a3k1 = *reinterpret_cast<const i32x8*>(abase + 48*D + 128);
    asm volatile("" : "+v"(a0k0), "+v"(a0k1), "+v"(a1k0), "+v"(a1k1),
                      "+v"(a2k0), "+v"(a2k1), "+v"(a3k0), "+v"(a3k1));

    f32x4 racc0 = {0.f,0.f,0.f,0.f}, racc1 = {0.f,0.f,0.f,0.f};
    f32x4 racc2 = {0.f,0.f,0.f,0.f}, racc3 = {0.f,0.f,0.f,0.f};
    float cacc[NG];   // per-LANE col partials; quad-reduce deferred to epilogue
#pragma unroll
    for (int n = 0; n < NG; ++n) cacc[n] = 0.f;

    __syncthreads();   // the ONLY barrier: staging DMA drained

    // Read swizzle (verified): col row = n*16+lrow, physical granule = logical^lrow.
    const int pe0 = (quad * 2) ^ lrow;
    const int pe1 = (8 + quad * 2) ^ lrow;
    const unsigned char* rbp = tb + lrow * D;

    // Group-0 reads (prologue of the 1-deep LDS pipeline).
    i32x4 plo0 = *reinterpret_cast<const i32x4*>(rbp + pe0*16);
    i32x4 phi0 = *reinterpret_cast<const i32x4*>(rbp + (pe0^1)*16);
    i32x4 plo1 = *reinterpret_cast<const i32x4*>(rbp + pe1*16);
    i32x4 phi1 = *reinterpret_cast<const i32x4*>(rbp + (pe1^1)*16);

#pragma unroll
    for (int n = 0; n < NG; ++n) {
        const i32x4 lo0 = plo0, hi0 = phi0, lo1 = plo1, hi1 = phi1;
        // Issue next group's reads before this group's MFMAs (overlap LDS latency).
        if (n + 1 < NG) {
            rbp += 16 * D;
            plo0 = *reinterpret_cast<const i32x4*>(rbp + pe0*16);
            phi0 = *reinterpret_cast<const i32x4*>(rbp + (pe0^1)*16);
            plo1 = *reinterpret_cast<const i32x4*>(rbp + pe1*16);
            phi1 = *reinterpret_cast<const i32x4*>(rbp + (pe1^1)*16);
        }
        const i32x8 b0 = __builtin_shufflevector(lo0, hi0, 0,1,2,3,4,5,6,7);
        const i32x8 b1 = __builtin_shufflevector(lo1, hi1, 0,1,2,3,4,5,6,7);

        f32x4 c0 = {0.f,0.f,0.f,0.f}, c1 = {0.f,0.f,0.f,0.f};
        f32x4 c2 = {0.f,0.f,0.f,0.f}, c3 = {0.f,0.f,0.f,0.f};
        c0 = MFMA8(a0k0, b0, c0);  c0 = MFMA8(a0k1, b1, c0);
        c1 = MFMA8(a1k0, b0, c1);  c1 = MFMA8(a1k1, b1, c1);
        c2 = MFMA8(a2k0, b0, c2);  c2 = MFMA8(a2k1, b1, c2);
        c3 = MFMA8(a3k0, b0, c3);  c3 = MFMA8(a3k1, b1, c3);

        const float e00=__builtin_amdgcn_exp2f(c0[0]), e01=__builtin_amdgcn_exp2f(c0[1]);
        const float e02=__builtin_amdgcn_exp2f(c0[2]), e03=__builtin_amdgcn_exp2f(c0[3]);
        const float e10=__builtin_amdgcn_exp2f(c1[0]), e11=__builtin_amdgcn_exp2f(c1[1]);
        const float e12=__builtin_amdgcn_exp2f(c1[2]), e13=__builtin_amdgcn_exp2f(c1[3]);
        const float e20=__builtin_amdgcn_exp2f(c2[0]), e21=__builtin_amdgcn_exp2f(c2[1]);
        const float e22=__builtin_amdgcn_exp2f(c2[2]), e23=__builtin_amdgcn_exp2f(c2[3]);
        const float e30=__builtin_amdgcn_exp2f(c3[0]), e31=__builtin_amdgcn_exp2f(c3[1]);
        const float e32=__builtin_amdgcn_exp2f(c3[2]), e33=__builtin_amdgcn_exp2f(c3[3]);

        racc0[0]+=e00; racc0[1]+=e01; racc0[2]+=e02; racc0[3]+=e03;
        racc1[0]+=e10; racc1[1]+=e11; racc1[2]+=e12; racc1[3]+=e13;
        racc2[0]+=e20; racc2[1]+=e21; racc2[2]+=e22; racc2[3]+=e23;
        racc3[0]+=e30; racc3[1]+=e31; racc3[2]+=e32; racc3[3]+=e33;

        // Per-lane col partial (16 rows of this lane's quad-slice); NO shfl here.
        cacc[n] = ((e00+e01)+(e02+e03)) + ((e10+e11)+(e12+e13))
                + ((e20+e21)+(e22+e23)) + ((e30+e31)+(e32+e33));
    }

    // Row sums -> S[rows of I]: reduce over lrow (col) bits.
#define REDUCE_ATOMIC(RV, M)                                                    \
    {                                                                           \
        _Pragma("unroll")                                                       \
        for (int j = 0; j < 4; ++j) {                                           \
            float v = (RV)[j];                                                  \
            v += __shfl_xor(v, 1);                                              \
            v += __shfl_xor(v, 2);                                              \
            v += __shfl_xor(v, 4);                                              \
            v += __shfl_xor(v, 8);                                              \
            if (lrow == 0) atomicAdd(&S[r0 + (M)*16 + quad*4 + j], v);          \
        }                                                                       \
    }
    REDUCE_ATOMIC(racc0, 0)
    REDUCE_ATOMIC(racc1, 1)
    REDUCE_ATOMIC(racc2, 2)
    REDUCE_ATOMIC(racc3, 3)
#undef REDUCE_ATOMIC

    // Col sums -> S[rows of J] (symmetry), off-diagonal only; quad-reduce here.
    if (offdiag) {
#pragma unroll
        for (int n = 0; n < NG; ++n) {
            float v = cacc[n];
            v += __shfl_xor(v, 16);
            v += __shfl_xor(v, 32);
            if (quad == 0) atomicAdd(&S[cbase + n*16 + lrow], v);
        }
    }
}

// Kernel C: loss_r = log(exp(p_r) + S_r - e^2) - p_r ; atomicAdd(out, blocksum/R2).
__global__ __launch_bounds__(256) void reduce_kernel(const float* __restrict__ S,
                                                     const float* __restrict__ pos,
                                                     float* __restrict__ out) {
    __shared__ float wsum[4];
    const int tid = threadIdx.x;
    const int r = blockIdx.x * 256 + tid;
    const float p = pos[r & (BB - 1)];
    float lsum = __logf(__expf(p) + S[r] - E2) - p;
#pragma unroll
    for (int off = 32; off; off >>= 1) lsum += __shfl_xor(lsum, off);
    if ((tid & 63) == 0) wsum[tid >> 6] = lsum;
    __syncthreads();
    if (tid == 0) {
        float t = wsum[0] + wsum[1] + wsum[2] + wsum[3];
        atomicAdd(out, t * (1.0f / (float)R2));
    }
}

extern "C" void kernel_launch(void* const* d_in, const int* in_sizes, int n_in,
                              void* d_out, int out_size, void* d_ws, size_t ws_size,
                              hipStream_t stream) {
    (void)in_sizes; (void)n_in; (void)out_size; (void)ws_size;
    const float* xi = (const float*)d_in[0];
    const float* xj = (const float*)d_in[1];
    float* out = (float*)d_out;

    unsigned char* z8 = (unsigned char*)d_ws;                                  // 8192*256 = 2 MB
    float* S   = (float*)((char*)d_ws + (size_t)R2 * D);                       // 32 KB
    float* pos = (float*)((char*)d_ws + (size_t)R2 * D + R2 * 4);              // 16 KB

    norm_kernel<<<BB / 4, 256, 0, stream>>>(xi, xj, (int*)z8, pos, S, out);
    sim_kernel<<<NBLK, 256, 0, stream>>>(z8, S);
    reduce_kernel<<<R2 / 256, 256, 0, stream>>>(S, pos, out);
}

// Round 17
// 87.883 us; speedup vs baseline: 1.3922x; 1.3922x over previous
//
#include <hip/hip_runtime.h>
#include <hip/hip_bf16.h>

typedef __attribute__((ext_vector_type(8))) int   i32x8;   // 32 B = fp8 MFMA A/B operand (8 VGPRs)
typedef __attribute__((ext_vector_type(4))) int   i32x4;
typedef __attribute__((ext_vector_type(4))) float f32x4;   // MFMA C/D

constexpr int BB = 4096;   // batch B
constexpr int D  = 256;    // feature dim
constexpr int R2 = 8192;   // 2B rows of z
constexpr int NSPLIT = 32; // column splits (256 cols per block)
constexpr int CPB = R2 / NSPLIT;        // 256 cols per block = 64 KB LDS
constexpr int NG  = CPB / 16;           // 16 n-groups of 16 cols per wave
// z pre-scaled by sqrt(2*log2(e)): dot = log2(e)*sim/TEMP -> exp2(dot) = exp(sim/TEMP).
constexpr float SCALE = 1.6986436005760381f;
constexpr float E2 = 7.38905609893065f;  // exp(2) == exp(diag sim)

// Async 16B/lane global->LDS DMA. LDS dest is wave-uniform base + lane*16 (HW);
// global source is per-lane.
__device__ __forceinline__ void async16(const unsigned char* g, unsigned char* l) {
    __builtin_amdgcn_global_load_lds(
        (const __attribute__((address_space(1))) void*)g,
        (__attribute__((address_space(3))) void*)l,
        16, 0, 0);
}

// Unit-scale (E8M0 127 = 2^0) MX-fp8 MFMA, fmt A/B = fp8-e4m3. Verified correct R5-R16.
#define MFMA8(A, B, C) \
    __builtin_amdgcn_mfma_scale_f32_16x16x128_f8f6f4((A), (B), (C), 0, 0, 0, 127, 0, 127)

// Kernel A: L2-normalize rows, scale by sqrt(2*log2e), store fp8-e4m3 z[8192][256];
// pos[k] = 2*cos(xi_k, xj_k) in fp32. One wave per pair k. Also zero-inits out[0].
__global__ __launch_bounds__(256) void norm_kernel(const float* __restrict__ xi,
                                                   const float* __restrict__ xj,
                                                   int* __restrict__ z8,
                                                   float* __restrict__ pos,
                                                   float* __restrict__ out) {
    const int wid = threadIdx.x >> 6, lane = threadIdx.x & 63;
    const int k = blockIdx.x * 4 + wid;
    if (blockIdx.x == 0 && threadIdx.x == 0) out[0] = 0.f;
    const float4* a4 = reinterpret_cast<const float4*>(xi + (size_t)k * D);
    const float4* b4 = reinterpret_cast<const float4*>(xj + (size_t)k * D);
    float4 a = a4[lane], b = b4[lane];
    float ssi = a.x*a.x + a.y*a.y + a.z*a.z + a.w*a.w;
    float ssj = b.x*b.x + b.y*b.y + b.z*b.z + b.w*b.w;
    float dot = a.x*b.x + a.y*b.y + a.z*b.z + a.w*b.w;
#pragma unroll
    for (int off = 32; off; off >>= 1) {
        ssi += __shfl_xor(ssi, off);
        ssj += __shfl_xor(ssj, off);
        dot += __shfl_xor(dot, off);
    }
    const float inv_i = 1.0f / fmaxf(sqrtf(ssi), 1e-12f);
    const float inv_j = 1.0f / fmaxf(sqrtf(ssj), 1e-12f);
    const float si = inv_i * SCALE, sj = inv_j * SCALE;
    int pi = __builtin_amdgcn_cvt_pk_fp8_f32(a.x*si, a.y*si, 0, false);
    pi     = __builtin_amdgcn_cvt_pk_fp8_f32(a.z*si, a.w*si, pi, true);
    int pj = __builtin_amdgcn_cvt_pk_fp8_f32(b.x*sj, b.y*sj, 0, false);
    pj     = __builtin_amdgcn_cvt_pk_fp8_f32(b.z*sj, b.w*sj, pj, true);
    z8[(size_t)k * 64 + lane]        = pi;
    z8[(size_t)(k + BB) * 64 + lane] = pj;
    if (lane == 0) pos[k] = dot * inv_i * inv_j * 2.0f;
}

// Kernel B: partial[split][r] = sum over this split's 256 columns c of exp(z_r . z_c).
// R14 configuration — the empirical optimum of the R8-R16 design-space search
// (total 88.0 us). Key ingredients, each validated by a failure elsewhere:
//   * 64 KB LDS tile hard-caps occupancy at 2 blocks/CU -> any allocation <=256
//     regs is occupancy-neutral -> no spill/remat pathology (R5-R13 failures);
//   * full-matrix 1024-block grid keeps a replacement stream behind the 2
//     resident blocks/CU -> machine stays busy (triangular R15/R16: 528 blocks,
//     no stream -> occupancy 4.8%, slower despite half the FLOPs);
//   * m=4 (4 waves x 64 rows) halves ds_reads/MFMA vs m=2;
//   * stage-once via verified DMA source-swizzle, ONE barrier, pure
//     ds_read+MFMA+exp loop, no in-loop cross-lane ops (R15's in-loop shfl hurt);
//   * plain-store partial epilogue (no atomics needed).
// fp8 layouts + unit scales + swizzles verified R5-R16; A-frag asm pin (R9/R10).
__global__ __launch_bounds__(256) void sim_kernel(const unsigned char* __restrict__ z8,
                                                  float* __restrict__ partial) {
    __shared__ unsigned char tb[CPB * D];   // 64 KB -> LDS-capped 2 blocks/CU
    const int tid = threadIdx.x;
    const int wid = tid >> 6, lane = tid & 63;
    const int lrow = lane & 15, quad = lane >> 4;
    const int r0 = blockIdx.x * 256 + wid * 64;       // this wave's 64 rows
    const int cbase = blockIdx.y * CPB;               // this block's 256 cols

    // Staging: round i stages rows i*16 + (tid>>4). Physical granule p = tid&15
    // (forced dest tb + i*4096 + tid*16) <- logical granule p ^ (row&15),
    // row&15 = tid>>4. 16 rounds x 4 KB = 64 KB.
    {
        const int srow16 = tid >> 4;                       // row & 15
        const int srcg   = (tid & 15) ^ srow16;
        const unsigned char* gs = z8 + (size_t)(cbase + srow16) * D + srcg * 16;
        unsigned char* ds = tb + tid * 16;
#pragma unroll
        for (int i = 0; i < 16; ++i)
            async16(gs + (size_t)i * 16 * D, ds + i * 4096);
    }

    // A fragments: 64 rows x K=256. Layout (16x16x128 f8f6f4): row = lane&15,
    // k-bytes = (lane>>4)*32 + linear; k-half 1 at +128. Pinned vs remat (R9/R10).
    const unsigned char* abase = z8 + (size_t)(r0 + lrow) * D + quad * 32;
    i32x8 a0k0 = *reinterpret_cast<const i32x8*>(abase             );
    i32x8 a0k1 = *reinterpret_cast<const i32x8*>(abase        + 128);
    i32x8 a1k0 = *reinterpret_cast<const i32x8*>(abase + 16*D      );
    i32x8 a1k1 = *reinterpret_cast<const i32x8*>(abase + 16*D + 128);
    i32x8 a2k0 = *reinterpret_cast<const i32x8*>(abase + 32*D      );
    i32x8 a2k1 = *reinterpret_cast<const i32x8*>(abase + 32*D + 128);
    i32x8 a3k0 = *reinterpret_cast<const i32x8*>(abase + 48*D      );
    i32x8 a3k1 = *reinterpret_cast<const i32x8*>(abase + 48*D + 128);
    asm volatile("" : "+v"(a0k0), "+v"(a0k1), "+v"(a1k0), "+v"(a1k1),
                      "+v"(a2k0), "+v"(a2k1), "+v"(a3k0), "+v"(a3k1));

    f32x4 racc0 = {0.f,0.f,0.f,0.f}, racc1 = {0.f,0.f,0.f,0.f};
    f32x4 racc2 = {0.f,0.f,0.f,0.f}, racc3 = {0.f,0.f,0.f,0.f};

    __syncthreads();   // the ONLY barrier: staging DMA drained, 64 KB tile complete

    // Pure-LDS loop: per group, 4 ds_read_b128 + 8 MFMA + 16 exp2. Read swizzle
    // (verified R8/R11/R12): col row = n*16+lrow, physical granule = logical^lrow;
    // b128 pairs (pe, pe^1) reassemble the 32-B operand halves.
    const int pe0 = (quad * 2) ^ lrow;        // k-half 0 even granule
    const int pe1 = (8 + quad * 2) ^ lrow;    // k-half 1 even granule
    const unsigned char* rbp = tb + lrow * D;
#pragma unroll 4
    for (int n = 0; n < NG; ++n) {
        const i32x4 lo0 = *reinterpret_cast<const i32x4*>(rbp + pe0*16);
        const i32x4 hi0 = *reinterpret_cast<const i32x4*>(rbp + (pe0^1)*16);
        const i32x4 lo1 = *reinterpret_cast<const i32x4*>(rbp + pe1*16);
        const i32x4 hi1 = *reinterpret_cast<const i32x4*>(rbp + (pe1^1)*16);
        rbp += 16 * D;
        const i32x8 b0 = __builtin_shufflevector(lo0, hi0, 0,1,2,3,4,5,6,7);
        const i32x8 b1 = __builtin_shufflevector(lo1, hi1, 0,1,2,3,4,5,6,7);

        f32x4 c0 = {0.f,0.f,0.f,0.f}, c1 = {0.f,0.f,0.f,0.f};
        f32x4 c2 = {0.f,0.f,0.f,0.f}, c3 = {0.f,0.f,0.f,0.f};
        c0 = MFMA8(a0k0, b0, c0);  c0 = MFMA8(a0k1, b1, c0);
        c1 = MFMA8(a1k0, b0, c1);  c1 = MFMA8(a1k1, b1, c1);
        c2 = MFMA8(a2k0, b0, c2);  c2 = MFMA8(a2k1, b1, c2);
        c3 = MFMA8(a3k0, b0, c3);  c3 = MFMA8(a3k1, b1, c3);

        racc0[0] += __builtin_amdgcn_exp2f(c0[0]);
        racc0[1] += __builtin_amdgcn_exp2f(c0[1]);
        racc0[2] += __builtin_amdgcn_exp2f(c0[2]);
        racc0[3] += __builtin_amdgcn_exp2f(c0[3]);
        racc1[0] += __builtin_amdgcn_exp2f(c1[0]);
        racc1[1] += __builtin_amdgcn_exp2f(c1[1]);
        racc1[2] += __builtin_amdgcn_exp2f(c1[2]);
        racc1[3] += __builtin_amdgcn_exp2f(c1[3]);
        racc2[0] += __builtin_amdgcn_exp2f(c2[0]);
        racc2[1] += __builtin_amdgcn_exp2f(c2[1]);
        racc2[2] += __builtin_amdgcn_exp2f(c2[2]);
        racc2[3] += __builtin_amdgcn_exp2f(c2[3]);
        racc3[0] += __builtin_amdgcn_exp2f(c3[0]);
        racc3[1] += __builtin_amdgcn_exp2f(c3[1]);
        racc3[2] += __builtin_amdgcn_exp2f(c3[2]);
        racc3[3] += __builtin_amdgcn_exp2f(c3[3]);
    }

    // Row sums: reduce over lane bits 0-3 (the col index); row = quad*4 + j.
#define REDUCE_STORE(RV, M)                                                     \
    {                                                                           \
        _Pragma("unroll")                                                       \
        for (int j = 0; j < 4; ++j) {                                           \
            float v = (RV)[j];                                                  \
            v += __shfl_xor(v, 1);                                              \
            v += __shfl_xor(v, 2);                                              \
            v += __shfl_xor(v, 4);                                              \
            v += __shfl_xor(v, 8);                                              \
            if (lrow == 0)                                                      \
                partial[(size_t)blockIdx.y * R2 + r0 + (M)*16 + quad*4 + j] = v;\
        }                                                                       \
    }
    REDUCE_STORE(racc0, 0)
    REDUCE_STORE(racc1, 1)
    REDUCE_STORE(racc2, 2)
    REDUCE_STORE(racc3, 3)
#undef REDUCE_STORE
}

// Kernel C: loss_r = log(exp(p_r) + S_r - e^2) - p_r ; atomicAdd(out, blocksum/R2).
// 32 blocks x 256 threads (256 rows each); out zero-initialized by norm_kernel.
__global__ __launch_bounds__(256) void reduce_kernel(const float* __restrict__ partial,
                                                     const float* __restrict__ pos,
                                                     float* __restrict__ out) {
    __shared__ float wsum[4];
    const int tid = threadIdx.x;
    const int r = blockIdx.x * 256 + tid;
    float S = 0.f;
#pragma unroll
    for (int s = 0; s < NSPLIT; ++s) S += partial[(size_t)s * R2 + r];
    const float p = pos[r & (BB - 1)];
    float lsum = __logf(__expf(p) + S - E2) - p;
#pragma unroll
    for (int off = 32; off; off >>= 1) lsum += __shfl_xor(lsum, off);
    if ((tid & 63) == 0) wsum[tid >> 6] = lsum;
    __syncthreads();
    if (tid == 0) {
        float t = wsum[0] + wsum[1] + wsum[2] + wsum[3];
        atomicAdd(out, t * (1.0f / (float)R2));
    }
}

extern "C" void kernel_launch(void* const* d_in, const int* in_sizes, int n_in,
                              void* d_out, int out_size, void* d_ws, size_t ws_size,
                              hipStream_t stream) {
    (void)in_sizes; (void)n_in; (void)out_size; (void)ws_size;
    const float* xi = (const float*)d_in[0];
    const float* xj = (const float*)d_in[1];
    float* out = (float*)d_out;

    unsigned char* z8 = (unsigned char*)d_ws;                                  // 8192*256 = 2 MB
    float* partial = (float*)((char*)d_ws + (size_t)R2 * D);                   // 32*8192*4 = 1 MB
    float* pos     = (float*)((char*)d_ws + (size_t)R2 * D + (size_t)NSPLIT*R2*4);  // 16 KB

    norm_kernel<<<BB / 4, 256, 0, stream>>>(xi, xj, (int*)z8, pos, out);
    sim_kernel<<<dim3(R2 / 256, NSPLIT), 256, 0, stream>>>(z8, partial);
    reduce_kernel<<<R2 / 256, 256, 0, stream>>>(partial, pos, out);
}

// Round 18
// 84.265 us; speedup vs baseline: 1.4520x; 1.0429x over previous
//
#include <hip/hip_runtime.h>
#include <hip/hip_bf16.h>

typedef __attribute__((ext_vector_type(8))) int   i32x8;   // 32 B = fp8 MFMA A/B operand (8 VGPRs)
typedef __attribute__((ext_vector_type(4))) int   i32x4;
typedef __attribute__((ext_vector_type(4))) float f32x4;   // MFMA C/D

constexpr int BB = 4096;   // batch B
constexpr int D  = 256;    // feature dim
constexpr int R2 = 8192;   // 2B rows of z
constexpr int NSPLIT = 32; // column splits (256 cols per block)
constexpr int CPB = R2 / NSPLIT;        // 256 cols per block = 64 KB LDS
constexpr int NG  = CPB / 16;           // 16 n-groups of 16 cols per wave
// z pre-scaled by sqrt(2*log2(e)): dot = log2(e)*sim/TEMP -> exp2(dot) = exp(sim/TEMP).
constexpr float SCALE = 1.6986436005760381f;
constexpr float E2 = 7.38905609893065f;  // exp(2) == exp(diag sim)

// Async 16B/lane global->LDS DMA. LDS dest is wave-uniform base + lane*16 (HW);
// global source is per-lane.
__device__ __forceinline__ void async16(const unsigned char* g, unsigned char* l) {
    __builtin_amdgcn_global_load_lds(
        (const __attribute__((address_space(1))) void*)g,
        (__attribute__((address_space(3))) void*)l,
        16, 0, 0);
}

// Unit-scale (E8M0 127 = 2^0) MX-fp8 MFMA, fmt A/B = fp8-e4m3. Verified correct R5-R17.
#define MFMA8(A, B, C) \
    __builtin_amdgcn_mfma_scale_f32_16x16x128_f8f6f4((A), (B), (C), 0, 0, 0, 127, 0, 127)

// Kernel A: L2-normalize rows, scale by sqrt(2*log2e), store fp8-e4m3 z[8192][256];
// pos[k] = 2*cos(xi_k, xj_k) in fp32. One wave per pair k. Also zero-inits out[0].
__global__ __launch_bounds__(256) void norm_kernel(const float* __restrict__ xi,
                                                   const float* __restrict__ xj,
                                                   int* __restrict__ z8,
                                                   float* __restrict__ pos,
                                                   float* __restrict__ out) {
    const int wid = threadIdx.x >> 6, lane = threadIdx.x & 63;
    const int k = blockIdx.x * 4 + wid;
    if (blockIdx.x == 0 && threadIdx.x == 0) out[0] = 0.f;
    const float4* a4 = reinterpret_cast<const float4*>(xi + (size_t)k * D);
    const float4* b4 = reinterpret_cast<const float4*>(xj + (size_t)k * D);
    float4 a = a4[lane], b = b4[lane];
    float ssi = a.x*a.x + a.y*a.y + a.z*a.z + a.w*a.w;
    float ssj = b.x*b.x + b.y*b.y + b.z*b.z + b.w*b.w;
    float dot = a.x*b.x + a.y*b.y + a.z*b.z + a.w*b.w;
#pragma unroll
    for (int off = 32; off; off >>= 1) {
        ssi += __shfl_xor(ssi, off);
        ssj += __shfl_xor(ssj, off);
        dot += __shfl_xor(dot, off);
    }
    const float inv_i = 1.0f / fmaxf(sqrtf(ssi), 1e-12f);
    const float inv_j = 1.0f / fmaxf(sqrtf(ssj), 1e-12f);
    const float si = inv_i * SCALE, sj = inv_j * SCALE;
    int pi = __builtin_amdgcn_cvt_pk_fp8_f32(a.x*si, a.y*si, 0, false);
    pi     = __builtin_amdgcn_cvt_pk_fp8_f32(a.z*si, a.w*si, pi, true);
    int pj = __builtin_amdgcn_cvt_pk_fp8_f32(b.x*sj, b.y*sj, 0, false);
    pj     = __builtin_amdgcn_cvt_pk_fp8_f32(b.z*sj, b.w*sj, pj, true);
    z8[(size_t)k * 64 + lane]        = pi;
    z8[(size_t)(k + BB) * 64 + lane] = pj;
    if (lane == 0) pos[k] = dot * inv_i * inv_j * 2.0f;
}

// Kernel B: partial[split][r] = sum over this split's 256 columns c of exp(z_r . z_c).
// R18 = the one untested combination of every validated ingredient:
//   * 64 KB LDS tile -> hard cap 2 blocks/CU (allocator honest by construction,
//     VGPR 184/0-spill proven in R15/R17);
//   * 512-thread blocks (8 waves x 32 rows, m=2): 2 resident blocks = 16 waves/CU
//     = 4 waves/SIMD — DOUBLE R14's latency hiding (R14's 2 waves/SIMD left the
//     MFMA pipe busy only ~23% of sim time; chains of ds_read ~120cyc -> MFMA ->
//     16 dependent exps were exposed);
//   * one barrier, pure ds_read+MFMA+exp loop, no in-loop cross-lane ops;
//   * 1024-block stream (grid 32x32) keeps replacement blocks behind residents.
// m=2 doubles ds_reads/MFMA: per-CU floors ds_read 10.2us > MFMA 7.4us > exp 3.4us.
// Register demand ~85 << the 128 budget at 4 waves/EU (R8-proven-clean regime).
// fp8 layouts + unit scales + swizzles verified R5-R17; A-frag asm pin (R9/R10).
__global__ __launch_bounds__(512) void sim_kernel(const unsigned char* __restrict__ z8,
                                                  float* __restrict__ partial) {
    __shared__ unsigned char tb[CPB * D];   // 64 KB -> LDS-capped 2 blocks/CU
    const int tid = threadIdx.x;
    const int wid = tid >> 6, lane = tid & 63;
    const int lrow = lane & 15, quad = lane >> 4;
    const int r0 = blockIdx.x * 256 + wid * 32;       // this wave's 32 rows
    const int cbase = blockIdx.y * CPB;               // this block's 256 cols

    // Staging: 8 rounds x 8 KB (512 thr x 16 B). Round i, thread tid writes
    // physical granule-linear i*512 + tid -> row r = i*32 + (tid>>4), physical
    // granule p = tid&15. Source logical granule = p ^ (r&15) = (tid&15)^((tid>>4)&15).
    {
        const int srcg = (tid & 15) ^ ((tid >> 4) & 15);
        const unsigned char* gs = z8 + (size_t)(cbase + (tid >> 4)) * D + srcg * 16;
        unsigned char* ds = tb + tid * 16;
#pragma unroll
        for (int i = 0; i < 8; ++i)
            async16(gs + (size_t)i * 32 * D, ds + i * 8192);
    }

    // A fragments: 32 rows x K=256. Layout (16x16x128 f8f6f4): row = lane&15,
    // k-bytes = (lane>>4)*32 + linear; k-half 1 at +128. Pinned vs remat (R9/R10).
    const unsigned char* abase = z8 + (size_t)(r0 + lrow) * D + quad * 32;
    i32x8 a0k0 = *reinterpret_cast<const i32x8*>(abase             );
    i32x8 a0k1 = *reinterpret_cast<const i32x8*>(abase        + 128);
    i32x8 a1k0 = *reinterpret_cast<const i32x8*>(abase + 16*D      );
    i32x8 a1k1 = *reinterpret_cast<const i32x8*>(abase + 16*D + 128);
    asm volatile("" : "+v"(a0k0), "+v"(a0k1), "+v"(a1k0), "+v"(a1k1));

    f32x4 racc0 = {0.f,0.f,0.f,0.f}, racc1 = {0.f,0.f,0.f,0.f};

    __syncthreads();   // the ONLY barrier: staging DMA drained, 64 KB tile complete

    // Pure-LDS loop: per group, 4 ds_read_b128 + 4 MFMA + 8 exp2. Read swizzle
    // (verified): col row = n*16+lrow, physical granule = logical ^ lrow;
    // b128 pairs (pe, pe^1) reassemble the 32-B operand halves.
    const int pe0 = (quad * 2) ^ lrow;        // k-half 0 even granule
    const int pe1 = (8 + quad * 2) ^ lrow;    // k-half 1 even granule
    const unsigned char* rbp = tb + lrow * D;
#pragma unroll 4
    for (int n = 0; n < NG; ++n) {
        const i32x4 lo0 = *reinterpret_cast<const i32x4*>(rbp + pe0*16);
        const i32x4 hi0 = *reinterpret_cast<const i32x4*>(rbp + (pe0^1)*16);
        const i32x4 lo1 = *reinterpret_cast<const i32x4*>(rbp + pe1*16);
        const i32x4 hi1 = *reinterpret_cast<const i32x4*>(rbp + (pe1^1)*16);
        rbp += 16 * D;
        const i32x8 b0 = __builtin_shufflevector(lo0, hi0, 0,1,2,3,4,5,6,7);
        const i32x8 b1 = __builtin_shufflevector(lo1, hi1, 0,1,2,3,4,5,6,7);

        f32x4 c0 = {0.f,0.f,0.f,0.f}, c1 = {0.f,0.f,0.f,0.f};
        c0 = MFMA8(a0k0, b0, c0);  c0 = MFMA8(a0k1, b1, c0);
        c1 = MFMA8(a1k0, b0, c1);  c1 = MFMA8(a1k1, b1, c1);

        racc0[0] += __builtin_amdgcn_exp2f(c0[0]);
        racc0[1] += __builtin_amdgcn_exp2f(c0[1]);
        racc0[2] += __builtin_amdgcn_exp2f(c0[2]);
        racc0[3] += __builtin_amdgcn_exp2f(c0[3]);
        racc1[0] += __builtin_amdgcn_exp2f(c1[0]);
        racc1[1] += __builtin_amdgcn_exp2f(c1[1]);
        racc1[2] += __builtin_amdgcn_exp2f(c1[2]);
        racc1[3] += __builtin_amdgcn_exp2f(c1[3]);
    }

    // Row sums: reduce over lane bits 0-3 (the col index); row = quad*4 + j.
#define REDUCE_STORE(RV, M)                                                     \
    {                                                                           \
        _Pragma("unroll")                                                       \
        for (int j = 0; j < 4; ++j) {                                           \
            float v = (RV)[j];                                                  \
            v += __shfl_xor(v, 1);                                              \
            v += __shfl_xor(v, 2);                                              \
            v += __shfl_xor(v, 4);                                              \
            v += __shfl_xor(v, 8);                                              \
            if (lrow == 0)                                                      \
                partial[(size_t)blockIdx.y * R2 + r0 + (M)*16 + quad*4 + j] = v;\
        }                                                                       \
    }
    REDUCE_STORE(racc0, 0)
    REDUCE_STORE(racc1, 1)
#undef REDUCE_STORE
}

// Kernel C: loss_r = log(exp(p_r) + S_r - e^2) - p_r ; atomicAdd(out, blocksum/R2).
// 32 blocks x 256 threads (256 rows each); out zero-initialized by norm_kernel.
__global__ __launch_bounds__(256) void reduce_kernel(const float* __restrict__ partial,
                                                     const float* __restrict__ pos,
                                                     float* __restrict__ out) {
    __shared__ float wsum[4];
    const int tid = threadIdx.x;
    const int r = blockIdx.x * 256 + tid;
    float S = 0.f;
#pragma unroll
    for (int s = 0; s < NSPLIT; ++s) S += partial[(size_t)s * R2 + r];
    const float p = pos[r & (BB - 1)];
    float lsum = __logf(__expf(p) + S - E2) - p;
#pragma unroll
    for (int off = 32; off; off >>= 1) lsum += __shfl_xor(lsum, off);
    if ((tid & 63) == 0) wsum[tid >> 6] = lsum;
    __syncthreads();
    if (tid == 0) {
        float t = wsum[0] + wsum[1] + wsum[2] + wsum[3];
        atomicAdd(out, t * (1.0f / (float)R2));
    }
}

extern "C" void kernel_launch(void* const* d_in, const int* in_sizes, int n_in,
                              void* d_out, int out_size, void* d_ws, size_t ws_size,
                              hipStream_t stream) {
    (void)in_sizes; (void)n_in; (void)out_size; (void)ws_size;
    const float* xi = (const float*)d_in[0];
    const float* xj = (const float*)d_in[1];
    float* out = (float*)d_out;

    unsigned char* z8 = (unsigned char*)d_ws;                                  // 8192*256 = 2 MB
    float* partial = (float*)((char*)d_ws + (size_t)R2 * D);                   // 32*8192*4 = 1 MB
    float* pos     = (float*)((char*)d_ws + (size_t)R2 * D + (size_t)NSPLIT*R2*4);  // 16 KB

    norm_kernel<<<BB / 4, 256, 0, stream>>>(xi, xj, (int*)z8, pos, out);
    sim_kernel<<<dim3(R2 / 256, NSPLIT), 512, 0, stream>>>(z8, partial);
    reduce_kernel<<<R2 / 256, 256, 0, stream>>>(partial, pos, out);
}